// Round 4
// baseline (181.661 us; speedup 1.0000x reference)
//
#include <hip/hip_runtime.h>
#include <hip/hip_bf16.h>

#define N_NODES 50000
#define N_EDGES 800000
#define D_IN 96
#define D_OUT 128
#define CAP 64              // deg ~ Poisson(16); P(deg>=64) ~ e^-41 -> no drops

#define SLICES 8
#define NODES_PER_SLICE 6250
#define SLICE_CAP 110000    // per-slice edge buffer; E/8 = 100k expected, 110k = +31 sigma
#define TAIL_STRIDE 32      // u32 stride between tail counters (128 B apart, no shared sector)

// K1 partition section: 625 blocks x 1280 edges (5 per thread)
#define EPT 5
#define EPB (256 * EPT)                             // 1280
#define PART_BLOCKS (N_EDGES / EPB)                 // 625 exactly

#define CONV_THREADS (N_NODES * 12)                 // 600000
#define CONV_BLOCKS ((CONV_THREADS + 255) / 256)    // 2344
#define WCONV_BLOCKS 12                             // 128*24 = 3072 = 12*256 tasks

// bin pass: 8 slices x 32 blocks; block owns 196 nodes, LDS bucket + LDS cursors
#define BIN_J 32
#define NPB_BIN 196                                 // 32*196 = 6272 >= 6250
#define BIN_BLOCKS (SLICES * BIN_J)                 // 256

// fused agg+gemm: 64 nodes per block (4 waves x 16-node MFMA tiles), XCD-aligned
#define NPB 64
#define SLICE_AG_BLOCKS ((NODES_PER_SLICE + NPB - 1) / NPB)   // 98
#define AG_BLOCKS (SLICES * SLICE_AG_BLOCKS)                  // 784
#define AH_PITCH 104        // u16/row (96 + 8 pad); 208 B = 13*16 B (b128-aligned)

typedef unsigned short u16;
typedef __attribute__((ext_vector_type(8))) short short8;   // 8 x bf16 (4 VGPRs)
typedef __attribute__((ext_vector_type(4))) float f32x4;

__device__ __forceinline__ u16 f2bf(float f) {
    unsigned u = __float_as_uint(f);
    unsigned r = (u + 0x7FFFu + ((u >> 16) & 1u)) >> 16;   // RNE
    return (u16)r;
}
__device__ __forceinline__ float bf2f(u16 h) {
    return __uint_as_float(((unsigned)h) << 16);
}

// ---------------------------------------------------------------------------
// K1: heterogeneous grid.
//   [0, PART_BLOCKS): edge partition by dst-slice. LDS histogram over 8 bins,
//     ONE global atomicAdd per (block, slice) to reserve a contiguous chunk
//     (8 per block, tails 128 B apart), then scatter packed (dl<<16|src) u32.
//     Replaces 800K device-scope atomics with 5K: R2 showed the fill time is
//     invariant under issue-side ILP -> throughput-bound on memory-side
//     atomic execution (cross-XCD L2 non-coherence forces RMW to the shared
//     point; 800K/45.6us = 17.5 G/s ceiling signature).
//   [.., +CONV_BLOCKS): xh = bf16(x) row-major.
//   [.., +WCONV_BLOCKS): Wfrag = bf16 B-fragment-layout [Wl|Wr] in global ws.
// ---------------------------------------------------------------------------
__global__ __launch_bounds__(256) void sage_part_conv(
    const int* __restrict__ src,
    const int* __restrict__ dst,
    const float* __restrict__ x,
    const float* __restrict__ Wl,
    const float* __restrict__ Wr,
    int* __restrict__ tail,
    unsigned* __restrict__ slicebuf,
    u16* __restrict__ xh,
    u16* __restrict__ Wfrag)
{
    __shared__ unsigned hist[SLICES];
    __shared__ unsigned base[SLICES];
    __shared__ unsigned cur[SLICES];

    const int b = blockIdx.x;
    const int tid = (int)threadIdx.x;

    if (b < PART_BLOCKS) {
        if (tid < SLICES) { hist[tid] = 0u; cur[tid] = 0u; }
        __syncthreads();

        int d[EPT], s[EPT], g[EPT];
        const int e0 = b * EPB + tid;
#pragma unroll
        for (int i = 0; i < EPT; i++) {             // coalesced batch loads
            d[i] = dst[e0 + i * 256];
            s[i] = src[e0 + i * 256];
        }
#pragma unroll
        for (int i = 0; i < EPT; i++) {
            g[i] = d[i] / NODES_PER_SLICE;          // magic-mul division
            atomicAdd(&hist[g[i]], 1u);             // LDS atomic (cheap)
        }
        __syncthreads();
        if (tid < SLICES)                           // 8 device atomics / block
            base[tid] = (unsigned)atomicAdd(&tail[tid * TAIL_STRIDE], (int)hist[tid]);
        __syncthreads();
#pragma unroll
        for (int i = 0; i < EPT; i++) {
            unsigned loc = atomicAdd(&cur[g[i]], 1u);       // LDS atomic
            unsigned pos = base[g[i]] + loc;
            unsigned dl = (unsigned)(d[i] - g[i] * NODES_PER_SLICE); // < 6250
            if (pos < SLICE_CAP)                     // 31-sigma guard
                slicebuf[(unsigned)g[i] * SLICE_CAP + pos] =
                    (dl << 16) | (unsigned)s[i];     // src < 50000 < 2^16
        }
    } else if (b < PART_BLOCKS + CONV_BLOCKS) {
        unsigned t = (unsigned)(b - PART_BLOCKS) * 256u + threadIdx.x;
        if (t >= (unsigned)CONV_THREADS) return;
        unsigned n = t / 12u;
        unsigned c8 = t - n * 12u;
        const float* p = x + (size_t)n * D_IN + c8 * 8u;
        short8 v;
#pragma unroll
        for (int i = 0; i < 8; i++) v[i] = (short)f2bf(p[i]);
        *(short8*)(xh + (size_t)n * D_IN + c8 * 8u) = v;
    } else {
        // W -> bf16 fragments: 128 j x 24 chunks (12 Wl + 12 Wr)
        int idx = (b - PART_BLOCKS - CONV_BLOCKS) * 256 + tid;   // < 3072
        int j = idx / 24;
        int c8 = idx - j * 24;
        int kc = c8 >> 2;
        int quad = c8 & 3;
        const float* wsrc = (c8 < 12) ? (Wl + (size_t)j * D_IN + c8 * 8)
                                      : (Wr + (size_t)j * D_IN + (c8 - 12) * 8);
        int jt = j >> 4;
        int col = j & 15;
        short8 v;
#pragma unroll
        for (int i = 0; i < 8; i++) v[i] = (short)f2bf(wsrc[i]);
        *(short8*)(Wfrag + (((jt * 6 + kc) * 64) + col + 16 * quad) * 8) = v;
    }
}

// ---------------------------------------------------------------------------
// K1b: bin pass. Block (g = blockIdx&7, j = blockIdx>>3) owns nodes
// [g*6250 + j*196, +196). Streams slice g's packed edge buffer (~400 KB,
// L2-resident on XCD g via the &7 heuristic) with uint4 loads; in-range
// edges append into an LDS bucket via LDS atomics. Copy-out is fully
// coalesced b128 stores + plain cursor stores. ZERO global atomics,
// zero scattered global stores.
// ---------------------------------------------------------------------------
__global__ __launch_bounds__(256) void sage_bin(
    const int* __restrict__ tail,
    const unsigned* __restrict__ slicebuf,
    int* __restrict__ cursor,
    u16* __restrict__ bucket)
{
    __shared__ __align__(16) u16 bkt[NPB_BIN * CAP];   // 25088 B
    __shared__ unsigned cnt[NPB_BIN];

    const int g = blockIdx.x & 7;
    const int j = blockIdx.x >> 3;                     // 0..31
    const int tid = (int)threadIdx.x;
    const int nlo = j * NPB_BIN;                       // local node base in slice
    const int nvalid = (NODES_PER_SLICE - nlo) < NPB_BIN ? (NODES_PER_SLICE - nlo)
                                                         : NPB_BIN;  // 196 or 174

    for (int r = tid; r < NPB_BIN; r += 256) cnt[r] = 0u;
    __syncthreads();

    int TAIL = tail[g * TAIL_STRIDE];
    if (TAIL > SLICE_CAP) TAIL = SLICE_CAP;
    const unsigned* sb = slicebuf + (size_t)g * SLICE_CAP;

    for (int e0 = tid * 4; e0 < TAIL; e0 += 1024) {    // coalesced uint4 stream
        uint4 v = *(const uint4*)(sb + e0);
        unsigned vv0 = v.x, vv1 = v.y, vv2 = v.z, vv3 = v.w;
#pragma unroll
        for (int k = 0; k < 4; k++) {
            unsigned w = (k == 0) ? vv0 : (k == 1) ? vv1 : (k == 2) ? vv2 : vv3;
            if (e0 + k < TAIL) {
                int r = (int)(w >> 16) - nlo;
                if (r >= 0 && r < NPB_BIN) {           // dl<6250 => r<nvalid
                    unsigned p = atomicAdd(&cnt[r], 1u);   // LDS atomic
                    if (p < CAP) bkt[r * CAP + p] = (u16)(w & 0xFFFFu);
                }
            }
        }
    }
    __syncthreads();

    const int nbase = g * NODES_PER_SLICE + nlo;
    for (int idx = tid; idx < nvalid * 8; idx += 256) { // coalesced b128 copy-out
        int r = idx >> 3, q = idx & 7;
        *(short8*)(bucket + (size_t)(nbase + r) * CAP + q * 8) =
            *(const short8*)(bkt + r * CAP + q * 8);
    }
    for (int r = tid; r < nvalid; r += 256)
        cursor[nbase + r] = (int)cnt[r];               // true deg (incl. >CAP)
}

// ---------------------------------------------------------------------------
// K2 (unchanged this round): aggregate 64 nodes into LDS Ah, then MFMA.
// XCD-aligned with fill slices: g = blockIdx&7.
// ---------------------------------------------------------------------------
__global__ __launch_bounds__(256) void sage_agg_gemm(
    const u16* __restrict__ xh,
    const int* __restrict__ cursor,
    const u16* __restrict__ bucket,
    const u16* __restrict__ Wfrag,
    const float* __restrict__ bl,
    float* __restrict__ out)
{
    __shared__ u16 Ah[NPB * AH_PITCH];      // 13312 B

    const int tid = threadIdx.x;
    const int g = blockIdx.x & 7;
    const int kblk = blockIdx.x >> 3;                 // [0, 98)
    const int n0 = g * NODES_PER_SLICE + kblk * NPB;
    const int hi_s = (g + 1) * NODES_PER_SLICE;       // slice end (<= N_NODES)

    // ---- phase A: aggregate the block's 64 nodes into Ah ----
#pragma unroll
    for (int rep = 0; rep < 3; rep++) {
        int task = rep * 256 + tid;          // 0..767
        int m = task / 12;
        int c8 = task - m * 12;
        int n = n0 + m;

        float acc[8];
#pragma unroll
        for (int i = 0; i < 8; i++) acc[i] = 0.0f;
        float invd = 0.0f;

        if (n < hi_s) {
            int deg = cursor[n];
            int degc = deg < CAP ? deg : CAP;
            const u16* brow = bucket + (size_t)n * CAP;
            int e = 0;
            for (; e + 8 <= degc; e += 8) {
                short8 id = *(const short8*)(brow + e);   // 8 indices, one b128
                short8 v[8];
#pragma unroll
                for (int q = 0; q < 8; q++) {
                    unsigned s = (u16)id[q];
                    v[q] = *(const short8*)(xh + s * (unsigned)D_IN + c8 * 8u);
                }
#pragma unroll
                for (int q = 0; q < 8; q++)
#pragma unroll
                    for (int i = 0; i < 8; i++) acc[i] += bf2f((u16)v[q][i]);
            }
            if (e + 4 <= degc) {
                unsigned s0 = brow[e + 0];
                unsigned s1 = brow[e + 1];
                unsigned s2 = brow[e + 2];
                unsigned s3 = brow[e + 3];
                short8 v0 = *(const short8*)(xh + s0 * (unsigned)D_IN + c8 * 8u);
                short8 v1 = *(const short8*)(xh + s1 * (unsigned)D_IN + c8 * 8u);
                short8 v2 = *(const short8*)(xh + s2 * (unsigned)D_IN + c8 * 8u);
                short8 v3 = *(const short8*)(xh + s3 * (unsigned)D_IN + c8 * 8u);
#pragma unroll
                for (int i = 0; i < 8; i++)
                    acc[i] += bf2f((u16)v0[i]) + bf2f((u16)v1[i])
                            + bf2f((u16)v2[i]) + bf2f((u16)v3[i]);
                e += 4;
            }
            for (; e < degc; e++) {
                unsigned s = brow[e];
                short8 v = *(const short8*)(xh + s * (unsigned)D_IN + c8 * 8u);
#pragma unroll
                for (int i = 0; i < 8; i++) acc[i] += bf2f((u16)v[i]);
            }
            invd = 1.0f / fmaxf((float)deg, 1.0f);
        }

        short8 o;
#pragma unroll
        for (int i = 0; i < 8; i++) o[i] = (short)f2bf(acc[i] * invd);
        *(short8*)(Ah + m * AH_PITCH + c8 * 8) = o;
    }
    __syncthreads();

    // ---- phase B: 16-node MFMA tile per wave ----
    const int wave = tid >> 6;
    const int lane = tid & 63;
    const int m16 = lane & 15;
    const int quad = lane >> 4;
    const int tilebase = n0 + wave * 16;
    if (tilebase >= hi_s) return;            // single barrier already passed

    int nn = tilebase + m16;
    nn = nn < hi_s ? nn : hi_s - 1;          // clamp A-row source (store guarded)

    const u16* arow = Ah + (wave * 16 + m16) * AH_PITCH + quad * 8;
    const u16* xrow = xh + (size_t)nn * D_IN + quad * 8;
    short8 a[6];
#pragma unroll
    for (int kc = 0; kc < 3; kc++) a[kc]     = *(const short8*)(arow + kc * 32);
#pragma unroll
    for (int kc = 0; kc < 3; kc++) a[3 + kc] = *(const short8*)(xrow + kc * 32);

#pragma unroll
    for (int jt = 0; jt < 8; jt++) {
        f32x4 acc = {0.0f, 0.0f, 0.0f, 0.0f};
#pragma unroll
        for (int kc = 0; kc < 6; kc++) {
            short8 bfrag = *(const short8*)(Wfrag + ((jt * 6 + kc) * 64 + lane) * 8);
            acc = __builtin_amdgcn_mfma_f32_16x16x32_bf16(a[kc], bfrag, acc, 0, 0, 0);
        }
        const int j = jt * 16 + m16;         // col = lane&15
        const float bj = bl[j];
#pragma unroll
        for (int r = 0; r < 4; r++) {
            int row = quad * 4 + r;
            int n = tilebase + row;
            if (n < hi_s)
                out[(size_t)n * D_OUT + j] = fmaxf(acc[r] + bj, 0.0f);
        }
    }
}

extern "C" void kernel_launch(void* const* d_in, const int* in_sizes, int n_in,
                              void* d_out, int out_size, void* d_ws, size_t ws_size,
                              hipStream_t stream) {
    const float* x   = (const float*)d_in[0];
    const int* eidx  = (const int*)d_in[1];
    const float* Wl  = (const float*)d_in[2];
    const float* bl  = (const float*)d_in[3];
    const float* Wr  = (const float*)d_in[4];
    float* out = (float*)d_out;

    const int* src = eidx;                // edge_index[0]
    const int* dst = eidx + N_EDGES;      // edge_index[1]

    // ws layout (byte offsets):
    //   tail      0         1,024 B   (8 counters, 128 B apart)
    //   slicebuf  1,024     3,520,000 B (8 x 110000 u32)
    //   bucket    3,521,024 6,400,000 B (50000 x 64 u16)   [128-aligned]
    //   xh        9,921,024 9,600,000 B (bf16 x)           [16-aligned]
    //   Wfrag    19,521,024    49,152 B
    //   cursor   19,570,176   200,000 B
    char* ws = (char*)d_ws;
    int*      tailp    = (int*)ws;
    unsigned* slicebuf = (unsigned*)(ws + 1024);
    u16*      bucket   = (u16*)(ws + 3521024);
    u16*      xh       = (u16*)(ws + 9921024);
    u16*      Wfrag    = (u16*)(ws + 19521024);
    int*      cursor   = (int*)(ws + 19570176);

    hipMemsetAsync(tailp, 0, SLICES * TAIL_STRIDE * sizeof(int), stream);

    {
        dim3 grid(PART_BLOCKS + CONV_BLOCKS + WCONV_BLOCKS);   // 2981
        sage_part_conv<<<grid, 256, 0, stream>>>(src, dst, x, Wl, Wr,
                                                 tailp, slicebuf, xh, Wfrag);
    }
    {
        dim3 grid(BIN_BLOCKS);                                 // 256
        sage_bin<<<grid, 256, 0, stream>>>(tailp, slicebuf, cursor, bucket);
    }
    {
        dim3 grid(AG_BLOCKS);                                  // 784
        sage_agg_gemm<<<grid, 256, 0, stream>>>(xh, cursor, bucket, Wfrag, bl, out);
    }
}

// Round 7
// 130.863 us; speedup vs baseline: 1.3882x; 1.3882x over previous
//
#include <hip/hip_runtime.h>
#include <hip/hip_bf16.h>

#define N_NODES 50000
#define N_EDGES 800000
#define D_IN 96
#define D_OUT 128
#define CAP 64              // deg ~ Poisson(16); P(deg>=64) ~ e^-41 -> no drops

// counting sort into 256 bins of 196 nodes each (bin granularity == pass-2
// block granularity, so pass 2 reads ONLY its own contiguous region).
#define N_BINS 256
#define NODES_PER_BIN 196                           // 256*196 = 50176 >= 50000
#define BIN_CAP 4096        // edges/bin; lambda=3125, sigma=56 -> +17 sigma
#define TAIL_STRIDE 16      // u32 stride between tail counters (64 B apart)

// K1 partition section: 256 blocks x 3125 edges (13 slots x 256 threads)
#define PART_EPB 3125
#define PART_BLOCKS (N_EDGES / PART_EPB)            // 256 exactly
#define PART_SLOTS 13                               // ceil(3125/256)

#define CONV_THREADS (N_NODES * 12)                 // 600000
#define CONV_BLOCKS ((CONV_THREADS + 255) / 256)    // 2344
#define WCONV_BLOCKS 12                             // 128*24 = 3072 = 12*256 tasks

// fused agg+gemm: 64 nodes per block (4 waves x 16-node MFMA tiles)
#define SLICES 8
#define NODES_PER_SLICE 6250
#define NPB 64
#define SLICE_AG_BLOCKS ((NODES_PER_SLICE + NPB - 1) / NPB)   // 98
#define AG_BLOCKS (SLICES * SLICE_AG_BLOCKS)                  // 784
#define AH_PITCH 104        // u16/row (96 + 8 pad); 208 B = 13*16 B (b128-aligned)

typedef unsigned short u16;
typedef __attribute__((ext_vector_type(8))) short short8;   // 8 x bf16 (4 VGPRs)
typedef __attribute__((ext_vector_type(4))) float f32x4;

__device__ __forceinline__ u16 f2bf(float f) {
    unsigned u = __float_as_uint(f);
    unsigned r = (u + 0x7FFFu + ((u >> 16) & 1u)) >> 16;   // RNE
    return (u16)r;
}
__device__ __forceinline__ float bf2f(u16 h) {
    return __uint_as_float(((unsigned)h) << 16);
}

// ---------------------------------------------------------------------------
// K1: heterogeneous grid.
//   [0, PART_BLOCKS): counting-sort partition into 256 node-bins.
//     13-slot ILP batch loads (R2-proven) -> LDS histogram over 256 bins ->
//     ONE chunk-reserve device atomic per (block, bin) = 65,536 total
//     (~3.7us at the measured 17.5 G/s memory-side atomic ceiling) ->
//     scatter packed (dl<<16|src) u32 in ~12-edge contiguous runs.
//     R4 lesson: 8-slice bins made pass 2 re-stream 32x redundant data at
//     1 block/CU (55us, HBM 1.8%). Bin granularity must match the consumer.
//   [.., +CONV_BLOCKS): xh = bf16(x) row-major.
//   [.., +WCONV_BLOCKS): Wfrag = bf16 B-fragment-layout [Wl|Wr] in global ws.
// ---------------------------------------------------------------------------
__global__ __launch_bounds__(256) void sage_part_conv(
    const int* __restrict__ src,
    const int* __restrict__ dst,
    const float* __restrict__ x,
    const float* __restrict__ Wl,
    const float* __restrict__ Wr,
    int* __restrict__ tail,
    unsigned* __restrict__ binbuf,
    u16* __restrict__ xh,
    u16* __restrict__ Wfrag)
{
    __shared__ unsigned hist[N_BINS];
    __shared__ unsigned base[N_BINS];
    __shared__ unsigned cur[N_BINS];

    const int b = blockIdx.x;
    const int tid = (int)threadIdx.x;

    if (b < PART_BLOCKS) {
        hist[tid] = 0u; cur[tid] = 0u;              // 256 threads cover 256 bins
        __syncthreads();

        const int ebase = b * PART_EPB;
        const int e0 = ebase + tid;
        int d[PART_SLOTS], s[PART_SLOTS], bn[PART_SLOTS];
#pragma unroll
        for (int i = 0; i < PART_SLOTS; i++) {      // coalesced batch loads
            int valid = (tid + i * 256) < PART_EPB;
            int e = valid ? (e0 + i * 256) : ebase;
            d[i] = dst[e];
            s[i] = src[e];
        }
#pragma unroll
        for (int i = 0; i < PART_SLOTS; i++) {
            bn[i] = d[i] / NODES_PER_BIN;           // magic-mul division
            if ((tid + i * 256) < PART_EPB)
                atomicAdd(&hist[bn[i]], 1u);        // LDS atomic (cheap)
        }
        __syncthreads();
        base[tid] = (unsigned)atomicAdd(&tail[tid * TAIL_STRIDE], (int)hist[tid]);
        __syncthreads();
#pragma unroll
        for (int i = 0; i < PART_SLOTS; i++) {
            if ((tid + i * 256) < PART_EPB) {
                unsigned loc = atomicAdd(&cur[bn[i]], 1u);   // LDS atomic
                unsigned pos = base[bn[i]] + loc;
                unsigned dl = (unsigned)(d[i] - bn[i] * NODES_PER_BIN); // <196
                if (pos < BIN_CAP)                  // 17-sigma guard
                    binbuf[(unsigned)bn[i] * BIN_CAP + pos] =
                        (dl << 16) | (unsigned)s[i];   // src < 50000 < 2^16
            }
        }
    } else if (b < PART_BLOCKS + CONV_BLOCKS) {
        unsigned t = (unsigned)(b - PART_BLOCKS) * 256u + threadIdx.x;
        if (t >= (unsigned)CONV_THREADS) return;
        unsigned n = t / 12u;
        unsigned c8 = t - n * 12u;
        const float* p = x + (size_t)n * D_IN + c8 * 8u;
        short8 v;
#pragma unroll
        for (int i = 0; i < 8; i++) v[i] = (short)f2bf(p[i]);
        *(short8*)(xh + (size_t)n * D_IN + c8 * 8u) = v;
    } else {
        // W -> bf16 fragments: 128 j x 24 chunks (12 Wl + 12 Wr)
        int idx = (b - PART_BLOCKS - CONV_BLOCKS) * 256 + tid;   // < 3072
        int j = idx / 24;
        int c8 = idx - j * 24;
        int kc = c8 >> 2;
        int quad = c8 & 3;
        const float* wsrc = (c8 < 12) ? (Wl + (size_t)j * D_IN + c8 * 8)
                                      : (Wr + (size_t)j * D_IN + (c8 - 12) * 8);
        int jt = j >> 4;
        int col = j & 15;
        short8 v;
#pragma unroll
        for (int i = 0; i < 8; i++) v[i] = (short)f2bf(wsrc[i]);
        *(short8*)(Wfrag + (((jt * 6 + kc) * 64) + col + 16 * quad) * 8) = v;
    }
}

// ---------------------------------------------------------------------------
// K1b: bin pass. Block j owns nodes [j*196, +196) and reads ONLY bin j's
// contiguous region (<=16 KB, every edge in-range by construction — no
// filtering waste, vs R4's 32x redundant slice re-stream). LDS-atomic
// bucket build, then fully-coalesced b128 copy-out. Zero global atomics.
// ---------------------------------------------------------------------------
__global__ __launch_bounds__(256) void sage_bin(
    const int* __restrict__ tail,
    const unsigned* __restrict__ binbuf,
    int* __restrict__ cursor,
    u16* __restrict__ bucket)
{
    __shared__ __align__(16) u16 bkt[NODES_PER_BIN * CAP];   // 25088 B
    __shared__ unsigned cnt[NODES_PER_BIN];

    const int j = blockIdx.x;                          // 0..255
    const int tid = (int)threadIdx.x;
    const int nbase = j * NODES_PER_BIN;
    const int nvalid = (N_NODES - nbase) < NODES_PER_BIN ? (N_NODES - nbase)
                                                         : NODES_PER_BIN;  // 196 or 20

    for (int r = tid; r < NODES_PER_BIN; r += 256) cnt[r] = 0u;
    __syncthreads();

    int TAIL = tail[j * TAIL_STRIDE];
    if (TAIL > BIN_CAP) TAIL = BIN_CAP;
    const unsigned* sb = binbuf + (size_t)j * BIN_CAP;

    for (int e0 = tid * 4; e0 < TAIL; e0 += 1024) {    // coalesced uint4 stream
        uint4 v = *(const uint4*)(sb + e0);            // e0+3 < BIN_CAP always
        unsigned vv0 = v.x, vv1 = v.y, vv2 = v.z, vv3 = v.w;
#pragma unroll
        for (int k = 0; k < 4; k++) {
            unsigned w = (k == 0) ? vv0 : (k == 1) ? vv1 : (k == 2) ? vv2 : vv3;
            if (e0 + k < TAIL) {
                unsigned r = w >> 16;                  // < 196 by construction
                if (r < NODES_PER_BIN) {
                    unsigned p = atomicAdd(&cnt[r], 1u);   // LDS atomic
                    if (p < CAP) bkt[r * CAP + p] = (u16)(w & 0xFFFFu);
                }
            }
        }
    }
    __syncthreads();

    for (int idx = tid; idx < nvalid * 8; idx += 256) { // coalesced b128 copy-out
        int r = idx >> 3, q = idx & 7;
        *(short8*)(bucket + (size_t)(nbase + r) * CAP + q * 8) =
            *(const short8*)(bkt + r * CAP + q * 8);
    }
    for (int r = tid; r < nvalid; r += 256)
        cursor[nbase + r] = (int)cnt[r];               // true deg (incl. >CAP)
}

// ---------------------------------------------------------------------------
// K2 (unchanged this round): aggregate 64 nodes into LDS Ah, then MFMA.
// ---------------------------------------------------------------------------
__global__ __launch_bounds__(256) void sage_agg_gemm(
    const u16* __restrict__ xh,
    const int* __restrict__ cursor,
    const u16* __restrict__ bucket,
    const u16* __restrict__ Wfrag,
    const float* __restrict__ bl,
    float* __restrict__ out)
{
    __shared__ u16 Ah[NPB * AH_PITCH];      // 13312 B

    const int tid = threadIdx.x;
    const int g = blockIdx.x & 7;
    const int kblk = blockIdx.x >> 3;                 // [0, 98)
    const int n0 = g * NODES_PER_SLICE + kblk * NPB;
    const int hi_s = (g + 1) * NODES_PER_SLICE;       // slice end (<= N_NODES)

    // ---- phase A: aggregate the block's 64 nodes into Ah ----
#pragma unroll
    for (int rep = 0; rep < 3; rep++) {
        int task = rep * 256 + tid;          // 0..767
        int m = task / 12;
        int c8 = task - m * 12;
        int n = n0 + m;

        float acc[8];
#pragma unroll
        for (int i = 0; i < 8; i++) acc[i] = 0.0f;
        float invd = 0.0f;

        if (n < hi_s) {
            int deg = cursor[n];
            int degc = deg < CAP ? deg : CAP;
            const u16* brow = bucket + (size_t)n * CAP;
            int e = 0;
            for (; e + 8 <= degc; e += 8) {
                short8 id = *(const short8*)(brow + e);   // 8 indices, one b128
                short8 v[8];
#pragma unroll
                for (int q = 0; q < 8; q++) {
                    unsigned s = (u16)id[q];
                    v[q] = *(const short8*)(xh + s * (unsigned)D_IN + c8 * 8u);
                }
#pragma unroll
                for (int q = 0; q < 8; q++)
#pragma unroll
                    for (int i = 0; i < 8; i++) acc[i] += bf2f((u16)v[q][i]);
            }
            if (e + 4 <= degc) {
                unsigned s0 = brow[e + 0];
                unsigned s1 = brow[e + 1];
                unsigned s2 = brow[e + 2];
                unsigned s3 = brow[e + 3];
                short8 v0 = *(const short8*)(xh + s0 * (unsigned)D_IN + c8 * 8u);
                short8 v1 = *(const short8*)(xh + s1 * (unsigned)D_IN + c8 * 8u);
                short8 v2 = *(const short8*)(xh + s2 * (unsigned)D_IN + c8 * 8u);
                short8 v3 = *(const short8*)(xh + s3 * (unsigned)D_IN + c8 * 8u);
#pragma unroll
                for (int i = 0; i < 8; i++)
                    acc[i] += bf2f((u16)v0[i]) + bf2f((u16)v1[i])
                            + bf2f((u16)v2[i]) + bf2f((u16)v3[i]);
                e += 4;
            }
            for (; e < degc; e++) {
                unsigned s = brow[e];
                short8 v = *(const short8*)(xh + s * (unsigned)D_IN + c8 * 8u);
#pragma unroll
                for (int i = 0; i < 8; i++) acc[i] += bf2f((u16)v[i]);
            }
            invd = 1.0f / fmaxf((float)deg, 1.0f);
        }

        short8 o;
#pragma unroll
        for (int i = 0; i < 8; i++) o[i] = (short)f2bf(acc[i] * invd);
        *(short8*)(Ah + m * AH_PITCH + c8 * 8) = o;
    }
    __syncthreads();

    // ---- phase B: 16-node MFMA tile per wave ----
    const int wave = tid >> 6;
    const int lane = tid & 63;
    const int m16 = lane & 15;
    const int quad = lane >> 4;
    const int tilebase = n0 + wave * 16;
    if (tilebase >= hi_s) return;            // single barrier already passed

    int nn = tilebase + m16;
    nn = nn < hi_s ? nn : hi_s - 1;          // clamp A-row source (store guarded)

    const u16* arow = Ah + (wave * 16 + m16) * AH_PITCH + quad * 8;
    const u16* xrow = xh + (size_t)nn * D_IN + quad * 8;
    short8 a[6];
#pragma unroll
    for (int kc = 0; kc < 3; kc++) a[kc]     = *(const short8*)(arow + kc * 32);
#pragma unroll
    for (int kc = 0; kc < 3; kc++) a[3 + kc] = *(const short8*)(xrow + kc * 32);

#pragma unroll
    for (int jt = 0; jt < 8; jt++) {
        f32x4 acc = {0.0f, 0.0f, 0.0f, 0.0f};
#pragma unroll
        for (int kc = 0; kc < 6; kc++) {
            short8 bfrag = *(const short8*)(Wfrag + ((jt * 6 + kc) * 64 + lane) * 8);
            acc = __builtin_amdgcn_mfma_f32_16x16x32_bf16(a[kc], bfrag, acc, 0, 0, 0);
        }
        const int j = jt * 16 + m16;         // col = lane&15
        const float bj = bl[j];
#pragma unroll
        for (int r = 0; r < 4; r++) {
            int row = quad * 4 + r;
            int n = tilebase + row;
            if (n < hi_s)
                out[(size_t)n * D_OUT + j] = fmaxf(acc[r] + bj, 0.0f);
        }
    }
}

extern "C" void kernel_launch(void* const* d_in, const int* in_sizes, int n_in,
                              void* d_out, int out_size, void* d_ws, size_t ws_size,
                              hipStream_t stream) {
    const float* x   = (const float*)d_in[0];
    const int* eidx  = (const int*)d_in[1];
    const float* Wl  = (const float*)d_in[2];
    const float* bl  = (const float*)d_in[3];
    const float* Wr  = (const float*)d_in[4];
    float* out = (float*)d_out;

    const int* src = eidx;                // edge_index[0]
    const int* dst = eidx + N_EDGES;      // edge_index[1]

    // ws layout (byte offsets):
    //   tail       0          16,384 B  (256 counters, 64 B apart)
    //   binbuf     16,384     4,194,304 B (256 x 4096 u32)
    //   bucket     4,210,688  6,400,000 B (50000 x 64 u16)  [128-aligned]
    //   xh        10,610,688  9,600,000 B (bf16 x)          [16-aligned]
    //   Wfrag     20,210,688     49,152 B
    //   cursor    20,259,840    200,000 B
    char* ws = (char*)d_ws;
    int*      tailp  = (int*)ws;
    unsigned* binbuf = (unsigned*)(ws + 16384);
    u16*      bucket = (u16*)(ws + 4210688);
    u16*      xh     = (u16*)(ws + 10610688);
    u16*      Wfrag  = (u16*)(ws + 20210688);
    int*      cursor = (int*)(ws + 20259840);

    hipMemsetAsync(tailp, 0, N_BINS * TAIL_STRIDE * sizeof(int), stream);

    {
        dim3 grid(PART_BLOCKS + CONV_BLOCKS + WCONV_BLOCKS);   // 2612
        sage_part_conv<<<grid, 256, 0, stream>>>(src, dst, x, Wl, Wr,
                                                 tailp, binbuf, xh, Wfrag);
    }
    {
        dim3 grid(N_BINS);                                     // 256
        sage_bin<<<grid, 256, 0, stream>>>(tailp, binbuf, cursor, bucket);
    }
    {
        dim3 grid(AG_BLOCKS);                                  // 784
        sage_agg_gemm<<<grid, 256, 0, stream>>>(xh, cursor, bucket, Wfrag, bl, out);
    }
}

// Round 9
// 124.641 us; speedup vs baseline: 1.4575x; 1.0499x over previous
//
#include <hip/hip_runtime.h>
#include <hip/hip_bf16.h>

#define N_NODES 50000
#define N_EDGES 800000
#define D_IN 96
#define D_OUT 128
#define CAP 64              // deg ~ Poisson(16); P(deg>=64) ~ e^-41 -> no drops

// Deterministic partition: bins of 64 nodes (== agg block), each
// (part-block, bin) cell owns a FIXED 24-slot sub-chunk of binbuf plus a
// plain-store count. Zero device atomics, zero memset (cnts fully
// overwritten each run). R2/R4 lessons: 800K device atomics = 45us wall
// (memory-side RMW ceiling ~17.5 G/s); bin granularity must match consumer.
#define NPB 64                                      // nodes per bin/agg block
#define N_BINS ((N_NODES + NPB - 1) / NPB)          // 782
#define CAP_SUB 24          // edges per (pblock,bin); lambda=4 -> P(ovf) ~3e-7
#define PART_EPB 3125
#define PART_BLOCKS (N_EDGES / PART_EPB)            // 256 exactly
#define PART_SLOTS 13                               // ceil(3125/256)

#define CONV_THREADS (N_NODES * 12)                 // 600000
#define CONV_BLOCKS ((CONV_THREADS + 255) / 256)    // 2344
#define WCONV_BLOCKS 12                             // 128*24 = 3072 = 12*256 tasks

#define AG_BLOCKS N_BINS                            // 782
#define AH_PITCH 104        // u16/row (96 + 8 pad); 208 B = 13*16 B (b128-aligned)

typedef unsigned short u16;
typedef __attribute__((ext_vector_type(8))) short short8;   // 8 x bf16 (4 VGPRs)
typedef __attribute__((ext_vector_type(4))) float f32x4;

__device__ __forceinline__ u16 f2bf(float f) {
    unsigned u = __float_as_uint(f);
    unsigned r = (u + 0x7FFFu + ((u >> 16) & 1u)) >> 16;   // RNE
    return (u16)r;
}
__device__ __forceinline__ float bf2f(u16 h) {
    return __uint_as_float(((unsigned)h) << 16);
}

// ---------------------------------------------------------------------------
// K1: heterogeneous grid.
//   [0, PART_BLOCKS): deterministic partition. 13-slot ILP batch loads
//     (R2-proven) -> LDS histogram over 782 bins (bin = d>>6, no division) ->
//     plain-store counts to cnts[bin][pblock] -> scatter packed (dl<<16|src)
//     into fixed sub-chunk binbuf[(bin*256+pb)*24 + loc]. NO device atomics,
//     NO memset dependency.
//   [.., +CONV_BLOCKS): xh = bf16(x) row-major.
//   [.., +WCONV_BLOCKS): Wfrag = bf16 B-fragment-layout [Wl|Wr] in global ws.
// ---------------------------------------------------------------------------
__global__ __launch_bounds__(256) void sage_part_conv(
    const int* __restrict__ src,
    const int* __restrict__ dst,
    const float* __restrict__ x,
    const float* __restrict__ Wl,
    const float* __restrict__ Wr,
    u16* __restrict__ cnts,
    unsigned* __restrict__ binbuf,
    u16* __restrict__ xh,
    u16* __restrict__ Wfrag)
{
    __shared__ unsigned hist[N_BINS];
    __shared__ unsigned cur[N_BINS];

    const int b = blockIdx.x;
    const int tid = (int)threadIdx.x;

    if (b < PART_BLOCKS) {
        for (int i = tid; i < N_BINS; i += 256) { hist[i] = 0u; cur[i] = 0u; }
        __syncthreads();

        const int ebase = b * PART_EPB;
        const int e0 = ebase + tid;
        int d[PART_SLOTS], s[PART_SLOTS];
#pragma unroll
        for (int i = 0; i < PART_SLOTS; i++) {      // coalesced batch loads
            int valid = (tid + i * 256) < PART_EPB;
            int e = valid ? (e0 + i * 256) : ebase;
            d[i] = dst[e];
            s[i] = src[e];
        }
#pragma unroll
        for (int i = 0; i < PART_SLOTS; i++) {
            if ((tid + i * 256) < PART_EPB)
                atomicAdd(&hist[d[i] >> 6], 1u);    // LDS atomic (cheap)
        }
        __syncthreads();
        for (int i = tid; i < N_BINS; i += 256)     // plain-store counts
            cnts[(size_t)i * PART_BLOCKS + b] = (u16)hist[i];
#pragma unroll
        for (int i = 0; i < PART_SLOTS; i++) {
            if ((tid + i * 256) < PART_EPB) {
                int bn = d[i] >> 6;
                unsigned dl = (unsigned)(d[i] & 63);
                unsigned loc = atomicAdd(&cur[bn], 1u);      // LDS atomic
                if (loc < CAP_SUB)                  // ~3e-7 overflow guard
                    binbuf[((unsigned)bn * PART_BLOCKS + (unsigned)b) * CAP_SUB
                           + loc] = (dl << 16) | (unsigned)s[i];
            }
        }
    } else if (b < PART_BLOCKS + CONV_BLOCKS) {
        unsigned t = (unsigned)(b - PART_BLOCKS) * 256u + threadIdx.x;
        if (t >= (unsigned)CONV_THREADS) return;
        unsigned n = t / 12u;
        unsigned c8 = t - n * 12u;
        const float* p = x + (size_t)n * D_IN + c8 * 8u;
        short8 v;
#pragma unroll
        for (int i = 0; i < 8; i++) v[i] = (short)f2bf(p[i]);
        *(short8*)(xh + (size_t)n * D_IN + c8 * 8u) = v;
    } else {
        // W -> bf16 fragments: 128 j x 24 chunks (12 Wl + 12 Wr)
        int idx = (b - PART_BLOCKS - CONV_BLOCKS) * 256 + tid;   // < 3072
        int j = idx / 24;
        int c8 = idx - j * 24;
        int kc = c8 >> 2;
        int quad = c8 & 3;
        const float* wsrc = (c8 < 12) ? (Wl + (size_t)j * D_IN + c8 * 8)
                                      : (Wr + (size_t)j * D_IN + (c8 - 12) * 8);
        int jt = j >> 4;
        int col = j & 15;
        short8 v;
#pragma unroll
        for (int i = 0; i < 8; i++) v[i] = (short)f2bf(wsrc[i]);
        *(short8*)(Wfrag + (((jt * 6 + kc) * 64) + col + 16 * quad) * 8) = v;
    }
}

// ---------------------------------------------------------------------------
// K2 (fused bin+agg+gemm): block j owns nodes [j*64, +64).
// Prologue: thread t ingests sub-chunk (j, pblock=t): 6 independent uint4
//   loads (96 B, all in flight), then fully-unrolled static-index appends
//   into an 8 KB LDS bucket via LDS atomics (rule #20: no runtime-indexed
//   register arrays). Kills the bucket/cursor global round-trip + a launch.
// Phase A: 768 tasks (node m, chunk c8), 3/thread; bucket rows read from
//   LDS (b128), 8 xh row-gathers in flight.
// Phase B: per-wave 16-node MFMA tile; A-frags Ah/xh, B-frags Wfrag
//   (L2-broadcast). C/D map col=lane&15, row=quad*4+r (m89/m91-verified).
// ---------------------------------------------------------------------------
__global__ __launch_bounds__(256) void sage_agg_gemm(
    const u16* __restrict__ xh,
    const u16* __restrict__ cnts,
    const unsigned* __restrict__ binbuf,
    const u16* __restrict__ Wfrag,
    const float* __restrict__ bl,
    float* __restrict__ out)
{
    __shared__ __align__(16) u16 bkt[NPB * CAP];    // 8192 B
    __shared__ unsigned cnt_l[NPB];
    __shared__ u16 Ah[NPB * AH_PITCH];              // 13312 B

    const int j = blockIdx.x;                       // bin == block
    const int tid = (int)threadIdx.x;
    const int n0 = j * NPB;

    if (tid < NPB) cnt_l[tid] = 0u;
    __syncthreads();

    // ---- prologue: ingest this bin's 256 sub-chunks (thread t = pblock t) --
    {
        unsigned cnt_t = cnts[(size_t)j * PART_BLOCKS + tid];
        const uint4* sc = (const uint4*)(binbuf
                          + ((size_t)j * PART_BLOCKS + tid) * CAP_SUB);
        uint4 q0 = sc[0], q1 = sc[1], q2 = sc[2], q3 = sc[3], q4 = sc[4], q5 = sc[5];
        unsigned buf[CAP_SUB];
        buf[0]=q0.x;  buf[1]=q0.y;  buf[2]=q0.z;  buf[3]=q0.w;
        buf[4]=q1.x;  buf[5]=q1.y;  buf[6]=q1.z;  buf[7]=q1.w;
        buf[8]=q2.x;  buf[9]=q2.y;  buf[10]=q2.z; buf[11]=q2.w;
        buf[12]=q3.x; buf[13]=q3.y; buf[14]=q3.z; buf[15]=q3.w;
        buf[16]=q4.x; buf[17]=q4.y; buf[18]=q4.z; buf[19]=q4.w;
        buf[20]=q5.x; buf[21]=q5.y; buf[22]=q5.z; buf[23]=q5.w;
        unsigned lim = cnt_t < CAP_SUB ? cnt_t : CAP_SUB;
#pragma unroll
        for (int e = 0; e < CAP_SUB; e++) {         // static indices only
            if ((unsigned)e < lim) {
                unsigned w = buf[e];
                unsigned r = w >> 16;               // local node, < 64
                unsigned p = atomicAdd(&cnt_l[r], 1u);
                if (p < CAP) bkt[r * CAP + p] = (u16)(w & 0xFFFFu);
            }
        }
    }
    __syncthreads();

    // ---- phase A: aggregate the block's 64 nodes into Ah ----
#pragma unroll
    for (int rep = 0; rep < 3; rep++) {
        int task = rep * 256 + tid;          // 0..767
        int m = task / 12;
        int c8 = task - m * 12;
        int n = n0 + m;

        float acc[8];
#pragma unroll
        for (int i = 0; i < 8; i++) acc[i] = 0.0f;
        float invd = 0.0f;

        if (n < N_NODES) {
            int deg = (int)cnt_l[m];
            int degc = deg < CAP ? deg : CAP;
            const u16* brow = bkt + m * CAP;        // LDS
            int e = 0;
            for (; e + 8 <= degc; e += 8) {
                short8 id = *(const short8*)(brow + e);   // one LDS b128
                short8 v[8];
#pragma unroll
                for (int q = 0; q < 8; q++) {
                    unsigned s = (u16)id[q];
                    v[q] = *(const short8*)(xh + s * (unsigned)D_IN + c8 * 8u);
                }
#pragma unroll
                for (int q = 0; q < 8; q++)
#pragma unroll
                    for (int i = 0; i < 8; i++) acc[i] += bf2f((u16)v[q][i]);
            }
            if (e + 4 <= degc) {
                unsigned s0 = brow[e + 0];
                unsigned s1 = brow[e + 1];
                unsigned s2 = brow[e + 2];
                unsigned s3 = brow[e + 3];
                short8 v0 = *(const short8*)(xh + s0 * (unsigned)D_IN + c8 * 8u);
                short8 v1 = *(const short8*)(xh + s1 * (unsigned)D_IN + c8 * 8u);
                short8 v2 = *(const short8*)(xh + s2 * (unsigned)D_IN + c8 * 8u);
                short8 v3 = *(const short8*)(xh + s3 * (unsigned)D_IN + c8 * 8u);
#pragma unroll
                for (int i = 0; i < 8; i++)
                    acc[i] += bf2f((u16)v0[i]) + bf2f((u16)v1[i])
                            + bf2f((u16)v2[i]) + bf2f((u16)v3[i]);
                e += 4;
            }
            for (; e < degc; e++) {
                unsigned s = brow[e];
                short8 v = *(const short8*)(xh + s * (unsigned)D_IN + c8 * 8u);
#pragma unroll
                for (int i = 0; i < 8; i++) acc[i] += bf2f((u16)v[i]);
            }
            invd = 1.0f / fmaxf((float)deg, 1.0f);
        }

        short8 o;
#pragma unroll
        for (int i = 0; i < 8; i++) o[i] = (short)f2bf(acc[i] * invd);
        *(short8*)(Ah + m * AH_PITCH + c8 * 8) = o;
    }
    __syncthreads();

    // ---- phase B: 16-node MFMA tile per wave ----
    const int wave = tid >> 6;
    const int lane = tid & 63;
    const int m16 = lane & 15;
    const int quad = lane >> 4;
    const int tilebase = n0 + wave * 16;
    if (tilebase >= N_NODES) return;         // all barriers already passed

    int nn = tilebase + m16;
    nn = nn < N_NODES ? nn : N_NODES - 1;    // clamp A-row source (store guarded)

    const u16* arow = Ah + (wave * 16 + m16) * AH_PITCH + quad * 8;
    const u16* xrow = xh + (size_t)nn * D_IN + quad * 8;
    short8 a[6];
#pragma unroll
    for (int kc = 0; kc < 3; kc++) a[kc]     = *(const short8*)(arow + kc * 32);
#pragma unroll
    for (int kc = 0; kc < 3; kc++) a[3 + kc] = *(const short8*)(xrow + kc * 32);

#pragma unroll
    for (int jt = 0; jt < 8; jt++) {
        f32x4 acc = {0.0f, 0.0f, 0.0f, 0.0f};
#pragma unroll
        for (int kc = 0; kc < 6; kc++) {
            short8 bfrag = *(const short8*)(Wfrag + ((jt * 6 + kc) * 64 + lane) * 8);
            acc = __builtin_amdgcn_mfma_f32_16x16x32_bf16(a[kc], bfrag, acc, 0, 0, 0);
        }
        const int jj = jt * 16 + m16;        // col = lane&15
        const float bj = bl[jj];
#pragma unroll
        for (int r = 0; r < 4; r++) {
            int row = quad * 4 + r;
            int n = tilebase + row;
            if (n < N_NODES)
                out[(size_t)n * D_OUT + jj] = fmaxf(acc[r] + bj, 0.0f);
        }
    }
}

extern "C" void kernel_launch(void* const* d_in, const int* in_sizes, int n_in,
                              void* d_out, int out_size, void* d_ws, size_t ws_size,
                              hipStream_t stream) {
    const float* x   = (const float*)d_in[0];
    const int* eidx  = (const int*)d_in[1];
    const float* Wl  = (const float*)d_in[2];
    const float* bl  = (const float*)d_in[3];
    const float* Wr  = (const float*)d_in[4];
    float* out = (float*)d_out;

    const int* src = eidx;                // edge_index[0]
    const int* dst = eidx + N_EDGES;      // edge_index[1]

    // ws layout (byte offsets) — no zero-init needed anywhere:
    //   binbuf    0          19,218,432 B (782*256*24 u32, fixed sub-chunks)
    //   cnts      19,218,432    400,384 B (782*256 u16, fully overwritten)
    //   xh        19,618,816  9,600,000 B (bf16 x)        [16-aligned]
    //   Wfrag     29,218,816     49,152 B                  [16-aligned]
    char* ws = (char*)d_ws;
    unsigned* binbuf = (unsigned*)ws;
    u16*      cnts   = (u16*)(ws + 19218432);
    u16*      xh     = (u16*)(ws + 19618816);
    u16*      Wfrag  = (u16*)(ws + 29218816);

    {
        dim3 grid(PART_BLOCKS + CONV_BLOCKS + WCONV_BLOCKS);   // 2612
        sage_part_conv<<<grid, 256, 0, stream>>>(src, dst, x, Wl, Wr,
                                                 cnts, binbuf, xh, Wfrag);
    }
    {
        dim3 grid(AG_BLOCKS);                                  // 782
        sage_agg_gemm<<<grid, 256, 0, stream>>>(xh, cnts, binbuf, Wfrag, bl, out);
    }
}